// Round 9
// baseline (227.404 us; speedup 1.0000x reference)
//
#include <hip/hip_runtime.h>
#include <hip/hip_bf16.h>

// LSTM cell, B=8192, IN=1024, H=1024.
// gates[8192,4096] = [x|h_prev] @ [Wf|Wi|Wu|Wo] + b ; fused epilogue -> h_t, c_t.
// Round 9: 3 blocks/CU (3 waves/SIMD TLP). Block = 4 waves (2Mx2N), tile
// 128 rows x 128 packed cols (per-wave 64x64, acc 64 regs -> ~130 unified
// VGPR -> 12 waves/CU). A AND B in LDS, ring-3 x 16KB = 48KB/block. Lead-2
// prefetch, counted vmcnt(4) (drains s+1, never 0), 1 barrier/slot.
// Theory: 2-way interleave (all prior rounds + m97) pins at ~912 TF; 3-way
// de-phased blocks overlap the ~balanced MFMA/LDS/vmem pipes.

typedef __attribute__((ext_vector_type(8))) short short8;   // 8 bf16
typedef __attribute__((ext_vector_type(4))) float f32x4;

#define GLOBAL_AS __attribute__((address_space(1)))
#define LDS_AS    __attribute__((address_space(3)))

__device__ __forceinline__ void load_lds16(const void* g, void* l) {
  // 16B/lane global->LDS DMA; LDS dest = wave-uniform base + lane*16 (linear)
  __builtin_amdgcn_global_load_lds((const GLOBAL_AS unsigned int*)g,
                                   (LDS_AS unsigned int*)l, 16, 0, 0);
}

__device__ __forceinline__ unsigned short f2bf(float f) {
  unsigned int u = __float_as_uint(f);
  return (unsigned short)((u + 0x7FFFu + ((u >> 16) & 1u)) >> 16);  // RNE
}
__device__ __forceinline__ float sigf(float x) { return 1.0f / (1.0f + __expf(-x)); }
__device__ __forceinline__ float tanh_fast(float x) {
  return 1.0f - 2.0f / (__expf(2.0f * x) + 1.0f);
}

// ---------------------------------------------------------------------------
// Merged pack kernel (R3's, verified):
//  blocks [0, 8192):    A = [x | h_prev] -> bf16 Apk[8192][2048], linear
//  blocks [8192,12288): W^T -> bf16 Wp[4096][2048], Wp[n][k] = W_g[k][n']
// ---------------------------------------------------------------------------
__global__ void pack_kernel(const float* __restrict__ x,
                            const float* __restrict__ h,
                            const float* __restrict__ W0,
                            const float* __restrict__ W1,
                            const float* __restrict__ W2,
                            const float* __restrict__ W3,
                            unsigned short* __restrict__ Apk,
                            unsigned short* __restrict__ Wp) {
  int blk = blockIdx.x;
  if (blk < 8192) {
    int t = blk * 256 + threadIdx.x;
    int row = t >> 8;
    int c   = t & 255;
    int k   = c << 3;
    const float* src = (k < 1024) ? (x + (size_t)row * 1024 + k)
                                  : (h + (size_t)row * 1024 + (k - 1024));
    float4 f0 = ((const float4*)src)[0];
    float4 f1 = ((const float4*)src)[1];
    union { unsigned short us[8]; uint4 v; } u;
    u.us[0] = f2bf(f0.x); u.us[1] = f2bf(f0.y);
    u.us[2] = f2bf(f0.z); u.us[3] = f2bf(f0.w);
    u.us[4] = f2bf(f1.x); u.us[5] = f2bf(f1.y);
    u.us[6] = f2bf(f1.z); u.us[7] = f2bf(f1.w);
    *(uint4*)(Apk + (size_t)row * 2048 + c * 8) = u.v;
  } else {
    int b  = blk - 8192;
    int c  = b & 255;          // k-chunk
    int nb = (b >> 8) & 3;     // n' block
    int g  = b >> 10;          // gate
    const float* Wg = (g == 0) ? W0 : (g == 1) ? W1 : (g == 2) ? W2 : W3;
    int np = nb * 256 + threadIdx.x;
    int kbase = c << 3;
    union { unsigned short us[8]; uint4 v; } u;
#pragma unroll
    for (int j = 0; j < 8; ++j)
      u.us[j] = f2bf(Wg[(size_t)(kbase + j) * 1024 + np]);
    int n = (g << 10) + np;
    *(uint4*)(Wp + (size_t)n * 2048 + c * 8) = u.v;
  }
}

// ---------------------------------------------------------------------------
// GEMM + LSTM epilogue. 4 waves (2M x 2N); per-wave 64 rows x 64 packed cols
// (= 16 h-cols x 4 gates). K=2048 -> 64 slots of 32. LDS ring-3: each ring
// holds A[128][32] (8KB) + B[128][32] (8KB). Per slot per wave: 4 DMA (s+2)
// + 8 ds_read_b128 + 16 MFMA + vmcnt(4) + barrier.
// ---------------------------------------------------------------------------
#define MFMA16(va, vb, vc) __builtin_amdgcn_mfma_f32_16x16x32_bf16(va, vb, vc, 0, 0, 0)

// S: slot index (expr); RR: ring of S (const 0..2); PR: ring of S+2 (const)
#define SLOT3(S, RR, PR)                                                       \
  {                                                                            \
    int sp_ = (S) + 2; sp_ = sp_ > 63 ? 63 : sp_;                              \
    const int so_ = sp_ * 32;                                                  \
    load_lds16(aSrc0 + so_, &LDSu[(PR) * 8192 + wv * 512]);                    \
    load_lds16(aSrc1 + so_, &LDSu[(PR) * 8192 + 2048 + wv * 512]);             \
    load_lds16(bSrc0 + so_, &LDSu[(PR) * 8192 + 4096 + wv * 512]);             \
    load_lds16(bSrc1 + so_, &LDSu[(PR) * 8192 + 4096 + 2048 + wv * 512]);      \
    short8 av[4], bv[4];                                                       \
    _Pragma("unroll")                                                          \
    for (int gg = 0; gg < 4; ++gg)                                             \
      bv[gg] = *(const short8*)&LDSu[(RR) * 8192 + 4096 + bRdBase + gg * 512]; \
    _Pragma("unroll")                                                          \
    for (int mm = 0; mm < 4; ++mm)                                             \
      av[mm] = *(const short8*)&LDSu[(RR) * 8192 + aRdBase + mm * 512];        \
    __builtin_amdgcn_s_setprio(1);                                             \
    _Pragma("unroll")                                                          \
    for (int mm = 0; mm < 4; ++mm) {                                           \
      _Pragma("unroll")                                                        \
      for (int gg = 0; gg < 4; ++gg)                                           \
        acc[mm][gg] = MFMA16(av[mm], bv[gg], acc[mm][gg]);                     \
    }                                                                          \
    __builtin_amdgcn_s_setprio(0);                                             \
    asm volatile("s_waitcnt vmcnt(4)");                                        \
    __builtin_amdgcn_s_barrier();                                              \
  }

__global__ __launch_bounds__(256, 3) void lstm_gemm_kernel(
    const unsigned short* __restrict__ Apk,   // [8192][2048] bf16
    const unsigned short* __restrict__ Wp,    // [4096][2048] bf16 (W^T)
    const float* __restrict__ c_prev,
    const float* __restrict__ bF, const float* __restrict__ bI,
    const float* __restrict__ bU, const float* __restrict__ bO,
    float* __restrict__ outH, float* __restrict__ outC) {
  __shared__ __align__(16) unsigned short LDSu[24576];   // 48 KB: 3 rings

  const int tid = threadIdx.x;
  const int l   = tid & 63;
  const int wv  = tid >> 6;        // wave 0..3
  const int wr  = wv >> 1;         // wave M index 0..1
  const int wc  = wv & 1;          // wave N index 0..1

  // XCD-bijective swizzle: 2048 blocks = 8 XCDs x 256
  int bid = blockIdx.x;
  int wg  = ((bid & 7) << 8) | (bid >> 3);
  const int mblk = wg >> 5;        // 0..63
  const int nblk = wg & 31;        // 0..31
  const int brow = mblk << 7;      // M base (x128)

  // --- ds_read addressing (ushort units). Rows are 32 us (one K-slot, 64B).
  // swizzled chunk sc = cg ^ ((rl>>1)&3); bank-parity split -> conflict-free.
  const int rl  = l & 15;
  const int cg  = l >> 4;                       // k-chunk group 0..3
  const int sc  = cg ^ ((rl >> 1) & 3);
  const int aRdBase = (wr * 64 + rl) * 32 + sc * 8;
  const int bRdBase = (wc * 64 + rl) * 32 + sc * 8;

  // --- staging source addressing. Call c covers LDS rows c*64 + wv*16 + l>>2;
  // global source chunk = (l&3) ^ ((row>>1)&3) = (l&3)^((l>>3)&3).
  const int csw = ((l & 3) ^ ((l >> 3) & 3)) * 8;
  const int ar0 = brow + wv * 16 + (l >> 2);
  const unsigned short* aSrc0 = Apk + (size_t)ar0 * 2048 + csw;
  const unsigned short* aSrc1 = aSrc0 + (size_t)64 * 2048;
  // B: LDS row j <-> packed col p = nblk*128 + j ; Wp row n decode:
  // p bits: rl(0-3) g(4-5) wc(6) nblk(7-11); n = g*1024 + (p>>6)*16 + (p&15)
  int p0 = nblk * 128 + wv * 16 + (l >> 2);
  int n0 = (((p0 >> 4) & 3) << 10) | ((p0 >> 6) << 4) | (p0 & 15);
  int p1 = p0 + 64;
  int n1 = (((p1 >> 4) & 3) << 10) | ((p1 >> 6) << 4) | (p1 & 15);
  const unsigned short* bSrc0 = Wp + (size_t)n0 * 2048 + csw;
  const unsigned short* bSrc1 = Wp + (size_t)n1 * 2048 + csw;

  f32x4 acc[4][4];                 // [m-frag][gate]
#pragma unroll
  for (int m = 0; m < 4; ++m)
#pragma unroll
    for (int g = 0; g < 4; ++g) acc[m][g] = (f32x4)0.0f;

  // --- prologue: stage slot 0 -> ring 0, slot 1 -> ring 1 (8 DMA)
#pragma unroll
  for (int s = 0; s < 2; ++s) {
    const int so = s * 32;
    load_lds16(aSrc0 + so, &LDSu[s * 8192 + wv * 512]);
    load_lds16(aSrc1 + so, &LDSu[s * 8192 + 2048 + wv * 512]);
    load_lds16(bSrc0 + so, &LDSu[s * 8192 + 4096 + wv * 512]);
    load_lds16(bSrc1 + so, &LDSu[s * 8192 + 4096 + 2048 + wv * 512]);
  }
  asm volatile("s_waitcnt vmcnt(4)");   // slot 0 landed; slot 1 in flight
  __builtin_amdgcn_s_barrier();

  // --- main loop: 64 slots = 21 x 3 + 1 (ring = s % 3 by unroll)
#pragma unroll 1
  for (int u = 0; u < 21; ++u) {
    const int s0 = 3 * u;
    SLOT3(s0,     0, 2)
    SLOT3(s0 + 1, 1, 0)
    SLOT3(s0 + 2, 2, 1)
  }
  SLOT3(63, 0, 2)

  // --- epilogue (register-local LSTM): frag g == gate g for the same h-col.
  const int colh = nblk * 32 + wc * 16 + rl;
  const float biasF = bF[colh], biasI = bI[colh];
  const float biasU = bU[colh], biasO = bO[colh];
  const int row0 = brow + wr * 64 + ((l >> 4) << 2);
#pragma unroll
  for (int m = 0; m < 4; ++m) {
#pragma unroll
    for (int r = 0; r < 4; ++r) {
      int row = row0 + m * 16 + r;
      size_t idx = (size_t)row * 1024 + colh;
      float f  = sigf(acc[m][0][r] + biasF);
      float i_ = sigf(acc[m][1][r] + biasI);
      float g_ = tanh_fast(acc[m][2][r] + biasU);
      float o_ = sigf(acc[m][3][r] + biasO);
      float cp = c_prev[idx];
      float cn = cp * f + i_ * g_;
      outH[idx] = o_ * tanh_fast(cn);
      outC[idx] = cn;
    }
  }
}

// ---------------------------------------------------------------------------
extern "C" void kernel_launch(void* const* d_in, const int* in_sizes, int n_in,
                              void* d_out, int out_size, void* d_ws, size_t ws_size,
                              hipStream_t stream) {
  const float* x      = (const float*)d_in[0];
  const float* h_prev = (const float*)d_in[1];
  const float* c_prev = (const float*)d_in[2];
  // d_in[3] = embed (unused by reference forward)
  const float* Wf = (const float*)d_in[4];
  const float* bf = (const float*)d_in[5];
  const float* Wi = (const float*)d_in[6];
  const float* bi = (const float*)d_in[7];
  const float* Wu = (const float*)d_in[8];
  const float* bu = (const float*)d_in[9];
  const float* Wo = (const float*)d_in[10];
  const float* bo = (const float*)d_in[11];

  unsigned short* Apk = (unsigned short*)d_ws;                                    // 32 MB
  unsigned short* Wp  = (unsigned short*)((char*)d_ws + (size_t)8192 * 2048 * 2); // 16 MB

  pack_kernel<<<12288, 256, 0, stream>>>(x, h_prev, Wf, Wi, Wu, Wo, Apk, Wp);

  float* outH = (float*)d_out;
  float* outC = outH + (size_t)8192 * 1024;
  lstm_gemm_kernel<<<2048, 256, 0, stream>>>(Apk, Wp, c_prev,
                                             bf, bi, bu, bo, outH, outC);
}